// Round 13
// baseline (1536.159 us; speedup 1.0000x reference)
//
#include <hip/hip_runtime.h>

#define EPSV 0.2f
#define USER_NUM 100000
#define ITEM_NUM 50000
#define NTOT 150000
#define NNZ_CNT 1200000
#define EMB 64

#define RPB 64                           // rows per bucket (LDS acc tile = 16 KB)
#define NBUCK ((NTOT + RPB - 1) / RPB)   // 2344
#define BLKA 512                         // blocks in passes A/C (2 blocks/CU)
#define SLICE_E ((NNZ_CNT + BLKA - 1) / BLKA)   // 2344 (last block short)

#define SCAN_M (NBUCK * BLKA)            // 1200128 flat count elements
#define SCAN_C 4096                      // elements per scan block
#define SCAN_G ((SCAN_M + SCAN_C - 1) / SCAN_C) // 293 (exact: 293*4096 = SCAN_M)

// clang ext_vector_types: valid operands for __builtin_nontemporal_load/store
// (HIP's float4/int2 are C++ classes and are rejected by the builtin).
typedef float v4f __attribute__((ext_vector_type(4)));
typedef int   v2i __attribute__((ext_vector_type(2)));

// ---- CSR-free build: bucket counting sort only (3 passes, no global atomics) ----
// R12 structural change: spmm is now EDGE-PARALLEL per bucket with an LDS
// accumulator tile, consuming bucket-grouped ebuf directly -> the final
// bucket->row sort pass (old pass D) and the csr/rowrange arrays are deleted.

// Pass A: per-block LDS histogram of its edge slice; transposed store.
__global__ __launch_bounds__(256) void bucket_count_kernel(const int* __restrict__ rows,
                                                           int* __restrict__ bcountT) {
    __shared__ int lh[NBUCK];
    const int t = threadIdx.x, blk = blockIdx.x;
    for (int b = t; b < NBUCK; b += 256) lh[b] = 0;
    __syncthreads();
    const int e0 = blk * SLICE_E;
    const int e1 = (e0 + SLICE_E < NNZ_CNT) ? e0 + SLICE_E : NNZ_CNT;
    for (int e = e0 + t; e < e1; e += 256)
        atomicAdd(&lh[rows[e] >> 6], 1);   // LDS atomic: CU-local, fast
    __syncthreads();
    // transposed: bucket-major flat layout for the device-wide scan
    for (int b = t; b < NBUCK; b += 256) bcountT[b * BLKA + blk] = lh[b];
}

// Scan: block-local exclusive scan (in place) of 4096-elem chunks + per-block
// total into partials. 293 blocks x 1024 threads, 4 elems/thread, coalesced.
__global__ __launch_bounds__(1024) void scan_local_kernel(int* __restrict__ data,
                                                          int* __restrict__ partials) {
    __shared__ int ws[16];
    const int t = threadIdx.x;
    const int base = blockIdx.x * SCAN_C + t * 4;
    int a0 = data[base + 0];
    int a1 = data[base + 1];
    int a2 = data[base + 2];
    int a3 = data[base + 3];
    int s = a0 + a1 + a2 + a3;
    int lane = t & 63, wid = t >> 6;
    int inc = s;
    #pragma unroll
    for (int off = 1; off < 64; off <<= 1) {
        int x = __shfl_up(inc, off, 64);
        if (lane >= off) inc += x;
    }
    if (lane == 63) ws[wid] = inc;
    __syncthreads();
    if (t < 16) {
        int w = ws[t];
        #pragma unroll
        for (int off = 1; off < 16; off <<= 1) {
            int x = __shfl_up(w, off, 64);
            if (t >= off) w += x;
        }
        ws[t] = w;
    }
    __syncthreads();
    int texcl = ((wid > 0) ? ws[wid - 1] : 0) + inc - s;  // exclusive thread prefix
    data[base + 0] = texcl;
    data[base + 1] = texcl + a0;
    data[base + 2] = texcl + a0 + a1;
    data[base + 3] = texcl + a0 + a1 + a2;
    if (t == 1023) partials[blockIdx.x] = texcl + s;      // block total
}

// Pass C: scatter edges into bucket-grouped ebuf. Cursor for (blk, bucket b) =
// scanned[b*BLKA + blk] + prefix(partials up to its chunk). Cursors in LDS,
// no global atomics. localrow (6b) packed into col bits 20..25.
// Block 0 additionally publishes bucketStart[b] = scanned value at (b, blk=0).
__global__ __launch_bounds__(256) void bucket_scatter_kernel(const int* __restrict__ rows,
                                                             const int* __restrict__ cols,
                                                             const float* __restrict__ vals,
                                                             const int* __restrict__ scanT,
                                                             const int* __restrict__ partials,
                                                             int* __restrict__ bucketStart,
                                                             int2* __restrict__ ebuf) {
    __shared__ int cur[NBUCK];
    __shared__ int pp[SCAN_G];
    const int t = threadIdx.x, blk = blockIdx.x;
    for (int i = t; i < SCAN_G; i += 256) pp[i] = partials[i];
    __syncthreads();
    if (t == 0) {
        int run = 0;
        for (int i = 0; i < SCAN_G; ++i) { int v = pp[i]; pp[i] = run; run += v; }
    }
    __syncthreads();
    for (int b = t; b < NBUCK; b += 256) {
        int idx = b * BLKA + blk;
        cur[b] = scanT[idx] + pp[idx >> 12];   // 4096 = 2^12
    }
    if (blk == 0) {
        for (int b = t; b < NBUCK; b += 256) {
            int idx = b * BLKA;
            bucketStart[b] = scanT[idx] + pp[idx >> 12];
        }
        if (t == 0) bucketStart[NBUCK] = NNZ_CNT;
    }
    __syncthreads();
    const int e0 = blk * SLICE_E;
    const int e1 = (e0 + SLICE_E < NNZ_CNT) ? e0 + SLICE_E : NNZ_CNT;
    for (int e = e0 + t; e < e1; e += 256) {
        int r = rows[e];
        int pos = atomicAdd(&cur[r >> 6], 1);  // LDS atomic
        ebuf[pos] = make_int2(cols[e] | ((r & 63) << 20), __float_as_int(vals[e]));
    }
}

// ---- Edge-parallel gather SpMM with LDS accumulation + fused perturbation ----
// One block per 64-row bucket. 16-lane groups process INDEPENDENT edges
// (2 per iteration, dual-issued gathers): broadcast 8B ebuf read -> 256B
// gather -> 4 ds_add_f32 into the LDS acc tile. No shfl chains, no per-row
// serialization, perfect load balance. Epilogue: perturb + write from LDS.
// FINAL_MODE (layer 2): final = (e1 + e2 + y)/3 (no accumulator RMW).
// Streaming traffic (noise, e1, final store) uses nontemporal hints.
template <bool CONCAT, bool FINAL_MODE>
__global__ __launch_bounds__(256)
void spmm_perturb_kernel(const float* __restrict__ src,
                         const float* __restrict__ user_emb,
                         const float* __restrict__ item_emb,
                         const int2* __restrict__ ebuf,
                         const int* __restrict__ bucketStart,
                         const float* __restrict__ noise_k,
                         const float* __restrict__ e1,
                         const float* __restrict__ e2,
                         float* __restrict__ out) {
    __shared__ float acc[RPB * EMB];          // 16 KB
    const int t = threadIdx.x;
    const int b = blockIdx.x;
    const int base = bucketStart[b];
    const int next = bucketStart[b + 1];
    v4f* acc4 = (v4f*)acc;
    #pragma unroll
    for (int i = 0; i < (RPB * EMB / 4) / 256; ++i)    // 4 iters
        acc4[t + i * 256] = (v4f)(0.f);
    __syncthreads();
    const int g = t >> 4;              // group 0..15
    const int q = t & 15;              // float4 slot within embedding row
    for (int i = base + g; i < next; i += 32) {        // 2 edges per iteration
        int2 ca = ebuf[i];                              // broadcast 8B load
        int ib = i + 16;
        bool hb = ib < next;
        int2 cb = hb ? ebuf[ib] : ca;                   // dup: same line, L1-hit
        int colA = ca.x & 0xFFFFF, lrA = (ca.x >> 20) & (RPB - 1);
        int colB = cb.x & 0xFFFFF, lrB = (cb.x >> 20) & (RPB - 1);
        float va = __int_as_float(ca.y);
        float vb = hb ? __int_as_float(cb.y) : 0.f;     // +0.0 adds are harmless
        const float *sa, *sb;
        if (CONCAT) {
            sa = (colA < USER_NUM) ? user_emb + (size_t)colA * EMB
                                   : item_emb + (size_t)(colA - USER_NUM) * EMB;
            sb = (colB < USER_NUM) ? user_emb + (size_t)colB * EMB
                                   : item_emb + (size_t)(colB - USER_NUM) * EMB;
        } else {
            sa = src + (size_t)colA * EMB;
            sb = src + (size_t)colB * EMB;
        }
        v4f xa = ((const v4f*)sa)[q];                   // both gathers in flight
        v4f xb = ((const v4f*)sb)[q];
        float* pa = acc + lrA * EMB + q * 4;
        float* pb = acc + lrB * EMB + q * 4;
        atomicAdd(pa + 0, va * xa.x);
        atomicAdd(pa + 1, va * xa.y);
        atomicAdd(pa + 2, va * xa.z);
        atomicAdd(pa + 3, va * xa.w);
        atomicAdd(pb + 0, vb * xb.x);
        atomicAdd(pb + 1, vb * xb.y);
        atomicAdd(pb + 2, vb * xb.z);
        atomicAdd(pb + 3, vb * xb.w);
    }
    __syncthreads();
    // epilogue: 4 passes x 16 rows (group g owns row pass*16+g)
    #pragma unroll
    for (int pass = 0; pass < RPB / 16; ++pass) {
        int lr = pass * 16 + g;
        int row = b * RPB + lr;
        if (row < NTOT) {
            size_t rowoff = (size_t)row * EMB;
            v4f a = ((v4f*)(acc + lr * EMB))[q];
            v4f nv = __builtin_nontemporal_load((const v4f*)(noise_k + rowoff) + q);
            float s = nv.x * nv.x + nv.y * nv.y + nv.z * nv.z + nv.w * nv.w;
            #pragma unroll
            for (int off = 8; off > 0; off >>= 1) s += __shfl_xor(s, off, 64);
            float scale = EPSV / fmaxf(sqrtf(s), 1e-12f);
            auto pert = [&](float av, float n) {
                float sg = (av > 0.f) ? 1.f : ((av < 0.f) ? -1.f : 0.f);
                return fmaf(sg * scale, n, av);
            };
            v4f y;
            y.x = pert(a.x, nv.x);
            y.y = pert(a.y, nv.y);
            y.z = pert(a.z, nv.z);
            y.w = pert(a.w, nv.w);
            if constexpr (FINAL_MODE) {
                v4f a1 = __builtin_nontemporal_load((const v4f*)(e1 + rowoff) + q);
                v4f a2 = ((const v4f*)(e2 + rowoff))[q];
                const float third = 1.f / 3.f;
                v4f f = (a1 + a2 + y) * third;
                __builtin_nontemporal_store(f, (v4f*)(out + rowoff) + q);  // never re-read
            } else {
                ((v4f*)(out + rowoff))[q] = y;  // cached: next layer gathers from this
            }
        }
    }
}

extern "C" void kernel_launch(void* const* d_in, const int* in_sizes, int n_in,
                              void* d_out, int out_size, void* d_ws, size_t ws_size,
                              hipStream_t stream) {
    const float* user_emb = (const float*)d_in[0];
    const float* item_emb = (const float*)d_in[1];
    const int*   adj_rows = (const int*)d_in[2];
    const int*   adj_cols = (const int*)d_in[3];
    const float* adj_vals = (const float*)d_in[4];
    const float* noise    = (const float*)d_in[5];

    float* out_final = (float*)d_out;                       // N x 64
    float* out_cl    = (float*)d_out + (size_t)NTOT * EMB;  // N x 64 (== ego after layer 0)

    // ws layout (persistent across the whole launch):
    char* p = (char*)d_ws;
    float* wsA         = (float*)p; p += (size_t)NTOT * EMB * sizeof(float); // 38.4 MB
    int2*  ebuf        = (int2*)p;  p += (size_t)NNZ_CNT * sizeof(int2);     // 9.6 MB (read by all 3 layers)
    int*   bucketStart = (int*)p;   p += (size_t)(NBUCK + 1) * sizeof(int);  // 9.4 KB

    // scan scratch aliases the front of wsA (dead after pass C; wsA is only
    // written by the layer-1 spmm, which runs after the build completes):
    int* scanT    = (int*)wsA;                 // 4.8 MB
    int* partials = scanT + SCAN_M;            // 293 ints

    // no memsets needed: scanT fully written by pass A, LDS hists zeroed on-chip
    bucket_count_kernel<<<BLKA, 256, 0, stream>>>(adj_rows, scanT);
    scan_local_kernel<<<SCAN_G, 1024, 0, stream>>>(scanT, partials);
    bucket_scatter_kernel<<<BLKA, 256, 0, stream>>>(adj_rows, adj_cols, adj_vals,
                                                    scanT, partials, bucketStart, ebuf);

    const size_t NE = (size_t)NTOT * EMB;

    // layer 0: src = concat(user,item) virtual -> ego1 to out_cl (cl output)
    spmm_perturb_kernel<true, false><<<NBUCK, 256, 0, stream>>>(
        nullptr, user_emb, item_emb, ebuf, bucketStart, noise + 0 * NE,
        nullptr, nullptr, out_cl);
    // layer 1: src = out_cl -> ego2 to wsA
    spmm_perturb_kernel<false, false><<<NBUCK, 256, 0, stream>>>(
        out_cl, nullptr, nullptr, ebuf, bucketStart, noise + 1 * NE,
        nullptr, nullptr, wsA);
    // layer 2: src = wsA -> y2; final = (ego1 + ego2 + y2)/3
    spmm_perturb_kernel<false, true><<<NBUCK, 256, 0, stream>>>(
        wsA, nullptr, nullptr, ebuf, bucketStart, noise + 2 * NE,
        out_cl, wsA, out_final);
}

// Round 14
// 394.874 us; speedup vs baseline: 3.8902x; 3.8902x over previous
//
#include <hip/hip_runtime.h>

#define EPSV 0.2f
#define USER_NUM 100000
#define ITEM_NUM 50000
#define NTOT 150000
#define NNZ_CNT 1200000
#define EMB 64

#define RPB 128                          // rows per bucket
#define NBUCK ((NTOT + RPB - 1) / RPB)   // 1172
#define BLKA 512                         // blocks in passes A/C (2 blocks/CU)
#define SLICE_E ((NNZ_CNT + BLKA - 1) / BLKA)   // 2344 (last block short)

#define SCAN_M (NBUCK * BLKA)            // 600064 flat count elements
#define SCAN_C 4096                      // elements per scan block
#define SCAN_G ((SCAN_M + SCAN_C - 1) / SCAN_C) // 147

// clang ext_vector_types: valid operands for __builtin_nontemporal_load/store
// (HIP's float4/int2 are C++ classes and are rejected by the builtin).
typedef float v4f __attribute__((ext_vector_type(4)));
typedef int   v2i __attribute__((ext_vector_type(2)));

// ---- CSR build via LDS-privatized two-level counting sort ----
// (R10: all build kernels below the top-5 cutoff; frozen.)
// R13 lesson: edge-parallel spmm with LDS accumulators serializes TWO
// dependent memory latencies per edge (ebuf read -> gather) and collapses
// MLP -> 444 us/layer. Row-parallel with 8 unrolled gathers stays.

// Pass A: per-block LDS histogram of its edge slice; transposed store.
__global__ __launch_bounds__(256) void bucket_count_kernel(const int* __restrict__ rows,
                                                           int* __restrict__ bcountT) {
    __shared__ int lh[NBUCK];
    const int t = threadIdx.x, blk = blockIdx.x;
    for (int b = t; b < NBUCK; b += 256) lh[b] = 0;
    __syncthreads();
    const int e0 = blk * SLICE_E;
    const int e1 = (e0 + SLICE_E < NNZ_CNT) ? e0 + SLICE_E : NNZ_CNT;
    for (int e = e0 + t; e < e1; e += 256)
        atomicAdd(&lh[rows[e] >> 7], 1);   // LDS atomic: CU-local, fast
    __syncthreads();
    // transposed: bucket-major flat layout for the device-wide scan
    for (int b = t; b < NBUCK; b += 256) bcountT[b * BLKA + blk] = lh[b];
}

// Scan: block-local exclusive scan (in place) of 4096-elem chunks + per-block
// total into partials. 147 blocks x 1024 threads, 4 elems/thread, coalesced.
__global__ __launch_bounds__(1024) void scan_local_kernel(int* __restrict__ data,
                                                          int* __restrict__ partials) {
    __shared__ int ws[16];
    const int t = threadIdx.x;
    const int base = blockIdx.x * SCAN_C + t * 4;
    int a0 = (base + 0 < SCAN_M) ? data[base + 0] : 0;
    int a1 = (base + 1 < SCAN_M) ? data[base + 1] : 0;
    int a2 = (base + 2 < SCAN_M) ? data[base + 2] : 0;
    int a3 = (base + 3 < SCAN_M) ? data[base + 3] : 0;
    int s = a0 + a1 + a2 + a3;
    int lane = t & 63, wid = t >> 6;
    int inc = s;
    #pragma unroll
    for (int off = 1; off < 64; off <<= 1) {
        int x = __shfl_up(inc, off, 64);
        if (lane >= off) inc += x;
    }
    if (lane == 63) ws[wid] = inc;
    __syncthreads();
    if (t < 16) {
        int w = ws[t];
        #pragma unroll
        for (int off = 1; off < 16; off <<= 1) {
            int x = __shfl_up(w, off, 64);
            if (t >= off) w += x;
        }
        ws[t] = w;
    }
    __syncthreads();
    int texcl = ((wid > 0) ? ws[wid - 1] : 0) + inc - s;  // exclusive thread prefix
    if (base + 0 < SCAN_M) data[base + 0] = texcl;
    if (base + 1 < SCAN_M) data[base + 1] = texcl + a0;
    if (base + 2 < SCAN_M) data[base + 2] = texcl + a0 + a1;
    if (base + 3 < SCAN_M) data[base + 3] = texcl + a0 + a1 + a2;
    if (t == 1023) partials[blockIdx.x] = texcl + s;      // block total
}

// Pass C: scatter edges into bucket-grouped ebuf. Cursor for (blk, bucket b) =
// scanned[b*BLKA + blk] + prefix(partials up to its chunk). Cursors in LDS,
// no global atomics. localrow (7b) packed into col bits 20..26.
__global__ __launch_bounds__(256) void bucket_scatter_kernel(const int* __restrict__ rows,
                                                             const int* __restrict__ cols,
                                                             const float* __restrict__ vals,
                                                             const int* __restrict__ scanT,
                                                             const int* __restrict__ partials,
                                                             int2* __restrict__ ebuf) {
    __shared__ int cur[NBUCK];
    __shared__ int pp[SCAN_G];
    const int t = threadIdx.x, blk = blockIdx.x;
    for (int i = t; i < SCAN_G; i += 256) pp[i] = partials[i];
    __syncthreads();
    if (t == 0) {
        int run = 0;
        for (int i = 0; i < SCAN_G; ++i) { int v = pp[i]; pp[i] = run; run += v; }
    }
    __syncthreads();
    for (int b = t; b < NBUCK; b += 256) {
        int idx = b * BLKA + blk;
        cur[b] = scanT[idx] + pp[idx >> 12];   // 4096 = 2^12
    }
    __syncthreads();
    const int e0 = blk * SLICE_E;
    const int e1 = (e0 + SLICE_E < NNZ_CNT) ? e0 + SLICE_E : NNZ_CNT;
    for (int e = e0 + t; e < e1; e += 256) {
        int r = rows[e];
        int pos = atomicAdd(&cur[r >> 7], 1);  // LDS atomic
        ebuf[pos] = make_int2(cols[e] | ((r & 127) << 20), __float_as_int(vals[e]));
    }
}

// Pass D: one block per bucket. base = scanned[b*BLKA] (+chunk prefix);
// LDS 128-row histogram + exclusive scan -> rowrange; in-bucket scatter to CSR.
__global__ __launch_bounds__(256) void bucket_csr_kernel(const int2* __restrict__ ebuf,
                                                         const int* __restrict__ scanT,
                                                         const int* __restrict__ partials,
                                                         int2* __restrict__ rowrange,
                                                         int2* __restrict__ csr) {
    __shared__ int h[RPB];
    __shared__ int c[RPB];
    __shared__ int wst[4];
    __shared__ int pp[SCAN_G];
    const int t = threadIdx.x, b = blockIdx.x;
    for (int i = t; i < SCAN_G; i += 256) pp[i] = partials[i];
    if (t < RPB) h[t] = 0;
    __syncthreads();
    if (t == 0) {
        int run = 0;
        for (int i = 0; i < SCAN_G; ++i) { int v = pp[i]; pp[i] = run; run += v; }
    }
    __syncthreads();
    int i0 = b * BLKA;
    const int base = scanT[i0] + pp[i0 >> 12];
    int next;
    if (b < NBUCK - 1) {
        int i1 = (b + 1) * BLKA;
        next = scanT[i1] + pp[i1 >> 12];
    } else {
        next = NNZ_CNT;
    }
    const int n = next - base;
    for (int i = t; i < n; i += 256)
        atomicAdd(&h[(ebuf[base + i].x >> 20) & 127], 1);
    __syncthreads();
    // exclusive scan of h[0..127] (waves 0,1 carry data; 2,3 compute zeros)
    int lane = t & 63, wid = t >> 6;
    int v = (t < RPB) ? h[t] : 0;
    int inc = v;
    #pragma unroll
    for (int off = 1; off < 64; off <<= 1) {
        int x = __shfl_up(inc, off, 64);
        if (lane >= off) inc += x;
    }
    if (lane == 63) wst[wid] = inc;
    __syncthreads();
    int woff = (wid == 1) ? wst[0] : 0;
    int excl = woff + inc - v;
    if (t < RPB) {
        c[t] = excl;
        int r0 = b * RPB + t;
        if (r0 < NTOT) rowrange[r0] = make_int2(base + excl, base + excl + v);
    }
    __syncthreads();
    for (int i = t; i < n; i += 256) {
        int2 cc = ebuf[base + i];
        int lr = (cc.x >> 20) & 127;
        int pos = atomicAdd(&c[lr], 1);  // LDS atomic
        csr[base + pos] = make_int2(cc.x & 0xFFFFF, cc.y);
    }
}

// ---- Gather SpMM fused with perturbation / accumulation ----
// 4 rows per wave: lane = (rsub<<4)|q, q = float4 index within the 64-elem row.
// csr batch: lane q loads edge (j+q) -> ONE coalesced 128B load per 16-edge
// batch per row-group; (col,val) distributed via __shfl from the owner lane.
// Gather loop is COMPILE-TIME UNROLLED in 8-edge chunks with predication
// (invalid slots clamp to edge 0's column, weight 0): 8 independent gathers
// in flight per group. Cross-batch csr prefetch for deg>16 rows.
// Natural register allocation (~56 VGPR): R11 showed forcing 8 waves/SIMD
// spills the accumulator (+167 MB scratch writes).
// FINAL_MODE (layer 2): epilogue computes final = (e1 + e2 + y)/3.
// Streaming traffic (noise, csr, e1, final store) uses nontemporal hints.
template <bool CONCAT, bool FINAL_MODE>
__global__ __launch_bounds__(256)
void spmm_perturb_kernel(const float* __restrict__ src,
                         const float* __restrict__ user_emb,
                         const float* __restrict__ item_emb,
                         const int2* __restrict__ rowrange,
                         const int2* __restrict__ csr,
                         const float* __restrict__ noise_k,
                         const float* __restrict__ e1,
                         const float* __restrict__ e2,
                         float* __restrict__ out) {
    int wid = threadIdx.x >> 6;        // wave in block: 0..3
    int lane = threadIdx.x & 63;
    int rsub = lane >> 4;              // 0..3 : row within wave
    int q = lane & 15;                 // float4 slot within row
    int row = blockIdx.x * 16 + wid * 4 + rsub;
    if (row >= NTOT) return;
    int2 rr = rowrange[row];
    int beg = rr.x, end = rr.y;
    size_t rowoff = (size_t)row * EMB;
    // streaming loads issued early (latency overlaps the gather loop)
    v4f nv = __builtin_nontemporal_load((const v4f*)(noise_k + rowoff) + q);
    v4f a1 = (v4f)(0.f);
    v4f a2 = (v4f)(0.f);
    if constexpr (FINAL_MODE) {
        a1 = __builtin_nontemporal_load((const v4f*)(e1 + rowoff) + q);  // not gathered again
        a2 = ((const v4f*)(e2 + rowoff))[q];  // cached: doubles as gather prefetch
    }
    const int grp = rsub << 4;         // first lane of this 16-lane group
    v4f acc = (v4f)(0.f);
    // prologue: load first batch
    v2i my = (v2i)(0);
    if (beg < end && beg + q < end)
        my = __builtin_nontemporal_load((const v2i*)csr + (beg + q));
    for (int j = beg; j < end; j += 16) {
        // prefetch next batch's csr while this batch computes
        v2i nxt = (v2i)(0);
        int jn = j + 16 + q;
        if (j + 16 < end && jn < end)
            nxt = __builtin_nontemporal_load((const v2i*)csr + jn);
        int c0 = __shfl(my.x, grp, 64);          // edge j: always valid here
        // two unrolled 8-edge chunks; break is group-uniform
        for (int half = 0; half < 2; ++half) {
            int u0 = half << 3;
            if (j + u0 >= end) break;
            int nval = end - j - u0; nval = (nval > 8) ? 8 : nval;  // 1..8, uniform
            #pragma unroll
            for (int u = 0; u < 8; ++u) {
                int cu = __shfl(my.x, grp + u0 + u, 64);
                float vu = __int_as_float(__shfl(my.y, grp + u0 + u, 64));
                bool ok = (u < nval);
                int c = ok ? cu : c0;            // dup of edge 0: same line, L2-hit
                float vv = ok ? vu : 0.f;
                const float* base;
                if (CONCAT)
                    base = (c < USER_NUM) ? (user_emb + (size_t)c * EMB)
                                          : (item_emb + (size_t)(c - USER_NUM) * EMB);
                else
                    base = src + (size_t)c * EMB;
                v4f x = ((const v4f*)base)[q];
                acc.x = fmaf(vv, x.x, acc.x);
                acc.y = fmaf(vv, x.y, acc.y);
                acc.z = fmaf(vv, x.z, acc.z);
                acc.w = fmaf(vv, x.w, acc.w);
            }
        }
        my = nxt;
    }
    // ||noise_row|| over the 16 lanes of this row group (xor 8,4,2,1 stays in-group)
    float s = nv.x * nv.x + nv.y * nv.y + nv.z * nv.z + nv.w * nv.w;
    #pragma unroll
    for (int off = 8; off > 0; off >>= 1) s += __shfl_xor(s, off, 64);
    float scale = EPSV / fmaxf(sqrtf(s), 1e-12f);
    auto pert = [&](float a, float n) {
        float sg = (a > 0.f) ? 1.f : ((a < 0.f) ? -1.f : 0.f);
        return fmaf(sg * scale, n, a);
    };
    v4f y;
    y.x = pert(acc.x, nv.x);
    y.y = pert(acc.y, nv.y);
    y.z = pert(acc.z, nv.z);
    y.w = pert(acc.w, nv.w);
    if constexpr (FINAL_MODE) {
        const float third = 1.f / 3.f;
        v4f f = (a1 + a2 + y) * third;
        __builtin_nontemporal_store(f, (v4f*)(out + rowoff) + q);  // never re-read
    } else {
        ((v4f*)(out + rowoff))[q] = y;  // cached: next layer gathers from this
    }
}

extern "C" void kernel_launch(void* const* d_in, const int* in_sizes, int n_in,
                              void* d_out, int out_size, void* d_ws, size_t ws_size,
                              hipStream_t stream) {
    const float* user_emb = (const float*)d_in[0];
    const float* item_emb = (const float*)d_in[1];
    const int*   adj_rows = (const int*)d_in[2];
    const int*   adj_cols = (const int*)d_in[3];
    const float* adj_vals = (const float*)d_in[4];
    const float* noise    = (const float*)d_in[5];

    float* out_final = (float*)d_out;                       // N x 64
    float* out_cl    = (float*)d_out + (size_t)NTOT * EMB;  // N x 64 (== ego after layer 0)

    // ws layout
    char* p = (char*)d_ws;
    float* wsA      = (float*)p;  p += (size_t)NTOT * EMB * sizeof(float); // 38.4 MB
    int2*  rowrange = (int2*)p;   p += (size_t)NTOT * sizeof(int2);        // 1.2 MB
    int2*  csr      = (int2*)p;   p += (size_t)NNZ_CNT * sizeof(int2);     // 9.6 MB

    // build scratch aliases the front of wsA (dead until the layer-1 spmm):
    char* q = (char*)wsA;
    int2* ebuf     = (int2*)q;  q += (size_t)NNZ_CNT * sizeof(int2);       // 9.6 MB
    int*  scanT    = (int*)q;   q += (size_t)SCAN_M * sizeof(int);         // 2.4 MB
    int*  partials = (int*)q;   q += 256 * sizeof(int);                    // 1 KB

    // no memsets needed: scanT fully written by pass A, LDS hists zeroed on-chip
    bucket_count_kernel<<<BLKA, 256, 0, stream>>>(adj_rows, scanT);
    scan_local_kernel<<<SCAN_G, 1024, 0, stream>>>(scanT, partials);
    bucket_scatter_kernel<<<BLKA, 256, 0, stream>>>(adj_rows, adj_cols, adj_vals,
                                                    scanT, partials, ebuf);
    bucket_csr_kernel<<<NBUCK, 256, 0, stream>>>(ebuf, scanT, partials,
                                                 rowrange, csr);

    const int spmm_blocks = (NTOT + 15) / 16;
    const size_t NE = (size_t)NTOT * EMB;

    // layer 0: src = concat(user,item) virtual -> ego1 to out_cl (cl output)
    spmm_perturb_kernel<true, false><<<spmm_blocks, 256, 0, stream>>>(
        nullptr, user_emb, item_emb, rowrange, csr, noise + 0 * NE,
        nullptr, nullptr, out_cl);
    // layer 1: src = out_cl -> ego2 to wsA
    spmm_perturb_kernel<false, false><<<spmm_blocks, 256, 0, stream>>>(
        out_cl, nullptr, nullptr, rowrange, csr, noise + 1 * NE,
        nullptr, nullptr, wsA);
    // layer 2: src = wsA -> y2; final = (ego1 + ego2 + y2)/3
    spmm_perturb_kernel<false, true><<<spmm_blocks, 256, 0, stream>>>(
        wsA, nullptr, nullptr, rowrange, csr, noise + 2 * NE,
        out_cl, wsA, out_final);
}